// Round 6
// baseline (85.655 us; speedup 1.0000x reference)
//
#include <hip/hip_runtime.h>

#define NW 10

// CNOT-ring fused permutation: psi_final[i] = psi_in[gperm(i)].
// Linear over GF(2): gperm(a^b) = gperm(a)^gperm(b).
__device__ __forceinline__ int gperm(int v) {
    #pragma unroll
    for (int k = 9; k >= 0; --k) {
        const int cs = 9 - k;                 // control bit (qubit k)
        const int ts = 9 - ((k + 1) % NW);    // target bit (qubit (k+1)%10)
        v ^= ((v >> cs) & 1) << ts;
    }
    return v;
}

// Padded float2-element index: vector b128 sides at bank floor, scalar b64
// sides even-4-way (= b64 bandwidth floor). Parity-preserving (16B alignment).
__device__ __forceinline__ int PQ(int i) {
    return i + ((i >> 4) << 1) + ((i >> 8) << 1);
}
#define PBUF 1156   // PQ(1022)+2 = 1156 float2 = 9248 B

// readlane: broadcast lane value -> wave-uniform (SGPR)
__device__ __forceinline__ float rl(float v, int lane) {
    return __int_as_float(__builtin_amdgcn_readlane(__float_as_int(v), lane));
}

// Single-wave workgroup: a wave executes in lockstep and the DS unit
// processes its LDS instructions in order, so cross-lane RAW through LDS
// needs only a compile-time ordering fence, not s_barrier + lgkmcnt(0) drain.
__device__ __forceinline__ void wave_fence() {
    __builtin_amdgcn_wave_barrier();
}

// Complex gate [[a,b],[-conj(b),conj(a)]] on register pairs (r, r+2^SH).
template<int SH>
__device__ __forceinline__ void cg(float* re, float* im,
                                   float ar, float ai, float br, float bi) {
    #pragma unroll
    for (int base = 0; base < 16; base += (2 << SH)) {
        #pragma unroll
        for (int off = 0; off < (1 << SH); ++off) {
            const int r0 = base + off, r1 = r0 + (1 << SH);
            const float v0r = re[r0], v0i = im[r0];
            const float v1r = re[r1], v1i = im[r1];
            re[r0] =  ar*v0r - ai*v0i + br*v1r - bi*v1i;
            im[r0] =  ar*v0i + ai*v0r + br*v1i + bi*v1r;
            re[r1] = -br*v0r - bi*v0i + ar*v1r + ai*v1i;
            im[r1] =  bi*v0r - br*v0i + ar*v1i - ai*v1r;
        }
    }
}

// Real RY gate [[c,-s],[s,c]] on register pairs (r, r+2^SH).
template<int SH>
__device__ __forceinline__ void rg(float* re, float* im, float c, float s) {
    #pragma unroll
    for (int base = 0; base < 16; base += (2 << SH)) {
        #pragma unroll
        for (int off = 0; off < (1 << SH); ++off) {
            const int r0 = base + off, r1 = r0 + (1 << SH);
            const float v0r = re[r0], v0i = im[r0];
            const float v1r = re[r1], v1i = im[r1];
            re[r0] = c*v0r - s*v1r;  im[r0] = c*v0i - s*v1i;
            re[r1] = s*v0r + c*v1r;  im[r1] = s*v0i + c*v1i;
        }
    }
}

// One wave (64 threads) per block = per state. 16 amps/lane.
// Layouts: L0: i = t<<4 | r;  L1: i = (t>>4)<<8 | r<<4 | (t&15);
//          L2: i = ((r>>2)&3)<<8 | t<<2 | (r&3).
__global__ __launch_bounds__(64) void qsa_main(
    const float* __restrict__ x,
    const float* __restrict__ rx0,
    const float* __restrict__ ry0,
    const float* __restrict__ ry1,
    float* __restrict__ out) {

    __shared__ __align__(16) float2 sp[PBUF];

    const int t = threadIdx.x;
    const int n = blockIdx.x;

    // ---- load row (L0 layout) ----
    float re[16], im[16];
    const float* xr = x + ((size_t)n << 10) + (t << 4);
    #pragma unroll
    for (int r = 0; r < 16; r += 4) {
        const float4 v = *reinterpret_cast<const float4*>(xr + r);
        re[r] = v.x; re[r+1] = v.y; re[r+2] = v.z; re[r+3] = v.w;
    }

    // ---- per-wire coefficients in lanes 0..9 (overlaps the x load) ----
    float car = 0.f, cai = 0.f, cbr = 0.f, cbi = 0.f, cc1 = 0.f, cs1 = 0.f;
    if (t < NW) {
        float sx, cx, sy0, cy0;
        sincosf(0.5f * rx0[t], &sx,  &cx);
        sincosf(0.5f * ry0[t], &sy0, &cy0);
        sincosf(0.5f * ry1[t], &cs1, &cc1);
        car =  cy0 * cx;  cai =  sy0 * sx;   // fused RY(ry0)*RX(rx0)
        cbr = -sy0 * cx;  cbi = -cy0 * sx;
    }

    // ---- sum of squares -> normalization ----
    float ss = 0.f;
    #pragma unroll
    for (int r = 0; r < 16; ++r) ss += re[r] * re[r];
    #pragma unroll
    for (int b = 32; b > 0; b >>= 1) ss += __shfl_xor(ss, b, 64);
    const float scale = 1.0f / fmaxf(sqrtf(ss), 1e-12f);

    // ========= layer 1, phase A (L0 bits 0-3 -> wires 9,8,7,6) =========
    {   // wire 9 (SH=0): input is real; fold in normalization
        const float ar = rl(car,9), ai = rl(cai,9), br = rl(cbr,9), bi = rl(cbi,9);
        #pragma unroll
        for (int r = 0; r < 16; r += 2) {
            const float v0 = re[r] * scale, v1 = re[r+1] * scale;
            re[r]   =  ar*v0 + br*v1;  im[r]   = ai*v0 + bi*v1;
            re[r+1] = -br*v0 + ar*v1;  im[r+1] = bi*v0 - ai*v1;
        }
    }
    cg<1>(re, im, rl(car,8), rl(cai,8), rl(cbr,8), rl(cbi,8));   // wire 8
    cg<2>(re, im, rl(car,7), rl(cai,7), rl(cbr,7), rl(cbi,7));   // wire 7
    cg<3>(re, im, rl(car,6), rl(cai,6), rl(cbr,6), rl(cbi,6));   // wire 6

    // T1: write L0 (b128), read L1 (b64) — no barrier, single-wave in-order DS
    #pragma unroll
    for (int r = 0; r < 16; r += 2)
        *reinterpret_cast<float4*>(&sp[PQ((t << 4) | r)]) =
            make_float4(re[r], im[r], re[r+1], im[r+1]);
    wave_fence();
    {
        const int b0 = ((t >> 4) << 8) | (t & 15);
        #pragma unroll
        for (int r = 0; r < 16; ++r) {
            const float2 v = sp[PQ(b0 + (r << 4))];
            re[r] = v.x; im[r] = v.y;
        }
    }

    // ========= layer 1, phase B (L1 bits 4-7 -> wires 5,4,3,2) =========
    cg<0>(re, im, rl(car,5), rl(cai,5), rl(cbr,5), rl(cbi,5));   // wire 5
    cg<1>(re, im, rl(car,4), rl(cai,4), rl(cbr,4), rl(cbi,4));   // wire 4
    cg<2>(re, im, rl(car,3), rl(cai,3), rl(cbr,3), rl(cbi,3));   // wire 3
    cg<3>(re, im, rl(car,2), rl(cai,2), rl(cbr,2), rl(cbi,2));   // wire 2

    // T2: write L1 (b64, own slots), read L2 (b128)
    wave_fence();
    {
        const int b0 = ((t >> 4) << 8) | (t & 15);
        #pragma unroll
        for (int r = 0; r < 16; ++r)
            sp[PQ(b0 + (r << 4))] = make_float2(re[r], im[r]);
    }
    wave_fence();
    #pragma unroll
    for (int r = 0; r < 16; r += 2) {
        const int i = ((r >> 2) << 8) | (t << 2) | (r & 3);
        const float4 q = *reinterpret_cast<const float4*>(&sp[PQ(i)]);
        re[r] = q.x; im[r] = q.y; re[r+1] = q.z; im[r+1] = q.w;
    }

    // ========= layer 1, phase C (L2: bit8=wire1, bit9=wire0) =========
    cg<2>(re, im, rl(car,1), rl(cai,1), rl(cbr,1), rl(cbi,1));   // wire 1
    cg<3>(re, im, rl(car,0), rl(cai,0), rl(cbr,0), rl(cbi,0));   // wire 0

    // T3: write L2 (b128, own slots), read CNOT-ring gather -> L0
    wave_fence();
    #pragma unroll
    for (int r = 0; r < 16; r += 2) {
        const int i = ((r >> 2) << 8) | (t << 2) | (r & 3);
        *reinterpret_cast<float4*>(&sp[PQ(i)]) =
            make_float4(re[r], im[r], re[r+1], im[r+1]);
    }
    wave_fence();
    {
        const int gt = gperm(t << 4);
        #pragma unroll
        for (int r = 0; r < 16; ++r) {
            const float2 v = sp[PQ(gt ^ gperm(r))];   // gperm(r) const-folds
            re[r] = v.x; im[r] = v.y;
        }
    }

    // ========= layer 2, phase A2 (L0 -> wires 9,8,7,6) =========
    rg<0>(re, im, rl(cc1,9), rl(cs1,9));   // wire 9
    rg<1>(re, im, rl(cc1,8), rl(cs1,8));   // wire 8
    rg<2>(re, im, rl(cc1,7), rl(cs1,7));   // wire 7
    rg<3>(re, im, rl(cc1,6), rl(cs1,6));   // wire 6

    // T4: write L0 (b128), read L1 (b64)
    wave_fence();
    #pragma unroll
    for (int r = 0; r < 16; r += 2)
        *reinterpret_cast<float4*>(&sp[PQ((t << 4) | r)]) =
            make_float4(re[r], im[r], re[r+1], im[r+1]);
    wave_fence();
    {
        const int b0 = ((t >> 4) << 8) | (t & 15);
        #pragma unroll
        for (int r = 0; r < 16; ++r) {
            const float2 v = sp[PQ(b0 + (r << 4))];
            re[r] = v.x; im[r] = v.y;
        }
    }

    // ========= layer 2, phase B2 (L1 -> wires 5,4,3,2) =========
    rg<0>(re, im, rl(cc1,5), rl(cs1,5));   // wire 5
    rg<1>(re, im, rl(cc1,4), rl(cs1,4));   // wire 4
    rg<2>(re, im, rl(cc1,3), rl(cs1,3));   // wire 3
    rg<3>(re, im, rl(cc1,2), rl(cs1,2));   // wire 2

    // T5: write L1 (b64, own slots), read L2 (b128)
    wave_fence();
    {
        const int b0 = ((t >> 4) << 8) | (t & 15);
        #pragma unroll
        for (int r = 0; r < 16; ++r)
            sp[PQ(b0 + (r << 4))] = make_float2(re[r], im[r]);
    }
    wave_fence();
    #pragma unroll
    for (int r = 0; r < 16; r += 2) {
        const int i = ((r >> 2) << 8) | (t << 2) | (r & 3);
        const float4 q = *reinterpret_cast<const float4*>(&sp[PQ(i)]);
        re[r] = q.x; im[r] = q.y; re[r+1] = q.z; im[r+1] = q.w;
    }

    // ========= layer 2, phase C2 (L2 -> wires 1,0) =========
    rg<2>(re, im, rl(cc1,1), rl(cs1,1));   // wire 1
    rg<3>(re, im, rl(cc1,0), rl(cs1,0));   // wire 0

    // ---- Z expectations (L2: i9i8 = r3r2, i7..2 = t, i1i0 = r1r0) ----
    float P = 0.f, a0 = 0.f, a1 = 0.f, a8 = 0.f, a9 = 0.f;
    #pragma unroll
    for (int r = 0; r < 16; ++r) {
        const float p = re[r] * re[r] + im[r] * im[r];
        P  += p;
        a0 += (r & 8) ? -p : p;   // wire 0 <- i bit 9 = r bit 3
        a1 += (r & 4) ? -p : p;   // wire 1 <- i bit 8 = r bit 2
        a8 += (r & 2) ? -p : p;   // wire 8 <- i bit 1 = r bit 1
        a9 += (r & 1) ? -p : p;   // wire 9 <- i bit 0 = r bit 0
    }
    #pragma unroll
    for (int b = 1; b < 64; b <<= 1) {
        a0 += __shfl_xor(a0, b, 64);
        a1 += __shfl_xor(a1, b, 64);
        a8 += __shfl_xor(a8, b, 64);
        a9 += __shfl_xor(a9, b, 64);
        const float e = __shfl_xor(P, b, 64);
        P = (t & b) ? (e - P) : (e + P);   // WHT over lane bits
    }
    float* o = out + (size_t)n * NW;
    if (t == 0) { o[0] = a0; o[1] = a1; o[8] = a8; o[9] = a9; }
    if (t == 32) o[2] = P;   // wire 2 <- t bit 5
    if (t == 16) o[3] = P;   // wire 3 <- t bit 4
    if (t ==  8) o[4] = P;   // wire 4 <- t bit 3
    if (t ==  4) o[5] = P;   // wire 5 <- t bit 2
    if (t ==  2) o[6] = P;   // wire 6 <- t bit 1
    if (t ==  1) o[7] = P;   // wire 7 <- t bit 0
}

extern "C" void kernel_launch(void* const* d_in, const int* in_sizes, int n_in,
                              void* d_out, int out_size, void* d_ws, size_t ws_size,
                              hipStream_t stream) {
    const float* x   = (const float*)d_in[0];
    const float* rx0 = (const float*)d_in[1];
    const float* ry0 = (const float*)d_in[2];
    const float* ry1 = (const float*)d_in[3];
    float* out = (float*)d_out;
    const int nstates = in_sizes[0] >> 10;   // 4096
    qsa_main<<<nstates, 64, 0, stream>>>(x, rx0, ry0, ry1, out);
}

// Round 7
// 81.479 us; speedup vs baseline: 1.0512x; 1.0512x over previous
//
#include <hip/hip_runtime.h>

#define NW 10
typedef float f32x2 __attribute__((ext_vector_type(2)));

__device__ __forceinline__ f32x2 swap2(f32x2 v) {
    return __builtin_shufflevector(v, v, 1, 0);
}

// CNOT-ring fused permutation: psi_final[i] = psi_in[gperm(i)].
// Linear over GF(2): gperm(a^b) = gperm(a)^gperm(b).
__device__ __forceinline__ int gperm(int v) {
    #pragma unroll
    for (int k = 9; k >= 0; --k) {
        const int cs = 9 - k;                 // control bit (qubit k)
        const int ts = 9 - ((k + 1) % NW);    // target bit (qubit (k+1)%10)
        v ^= ((v >> cs) & 1) << ts;
    }
    return v;
}

// Two-level padded float index (R3-proven): scalar trip sides 2-way (free),
// vector sides at bandwidth floor; 16B alignment kept (pad terms %4==0).
__device__ __forceinline__ int PF(int i) {
    return i + ((i >> 5) << 2) + ((i >> 8) << 3);
}
#define PBUF 1176   // max PF(1023) = 1171

// readlane: broadcast lane value -> wave-uniform (SGPR)
__device__ __forceinline__ float rl(float v, int lane) {
    return __int_as_float(__builtin_amdgcn_readlane(__float_as_int(v), lane));
}

// ---- packed complex gate [[a,b],[-conj(b),conj(a)]], f32x2 distance D ----
template<int D>
__device__ __forceinline__ void cgv(f32x2* rf, f32x2* mf,
                                    float ar, float ai, float br, float bi) {
    #pragma unroll
    for (int base = 0; base < 8; base += 2 * D) {
        #pragma unroll
        for (int off = 0; off < D; ++off) {
            const int j0 = base + off, j1 = j0 + D;
            const f32x2 v0r = rf[j0], v0i = mf[j0];
            const f32x2 v1r = rf[j1], v1i = mf[j1];
            rf[j0] = ar*v0r - ai*v0i + br*v1r - bi*v1i;
            mf[j0] = ar*v0i + ai*v0r + br*v1i + bi*v1r;
            rf[j1] = ar*v1r + ai*v1i - br*v0r - bi*v0i;
            mf[j1] = ar*v1i - ai*v1r - br*v0i + bi*v0r;
        }
    }
}

// packed complex gate acting WITHIN each f32x2 (amp-pair in one vector)
__device__ __forceinline__ void cgv0(f32x2* rf, f32x2* mf,
                                     float ar, float ai, float br, float bi) {
    const f32x2 aiN = {-ai,  ai};
    const f32x2 brN = { br, -br};
    #pragma unroll
    for (int j = 0; j < 8; ++j) {
        const f32x2 vr = rf[j], vi = mf[j];
        rf[j] = ar*vr + aiN*vi + brN*swap2(vr) - bi*swap2(vi);
        mf[j] = ar*vi - aiN*vr + brN*swap2(vi) + bi*swap2(vr);
    }
}

// ---- packed real RY gate [[c,-s],[s,c]], f32x2 distance D ----
template<int D>
__device__ __forceinline__ void rgv(f32x2* rf, f32x2* mf, float c, float s) {
    #pragma unroll
    for (int base = 0; base < 8; base += 2 * D) {
        #pragma unroll
        for (int off = 0; off < D; ++off) {
            const int j0 = base + off, j1 = j0 + D;
            const f32x2 v0r = rf[j0], v0i = mf[j0];
            const f32x2 v1r = rf[j1], v1i = mf[j1];
            rf[j0] = c*v0r - s*v1r;  mf[j0] = c*v0i - s*v1i;
            rf[j1] = s*v0r + c*v1r;  mf[j1] = s*v0i + c*v1i;
        }
    }
}

// packed real RY gate acting WITHIN each f32x2
__device__ __forceinline__ void rgv0(f32x2* rf, f32x2* mf, float c, float s) {
    const f32x2 sN = {-s, s};
    #pragma unroll
    for (int j = 0; j < 8; ++j) {
        rf[j] = c*rf[j] + sN*swap2(rf[j]);
        mf[j] = c*mf[j] + sN*swap2(mf[j]);
    }
}

// One wave (64 threads) per block = per state. 16 amps/lane as 8 f32x2 pairs.
// Layouts: L0: i = t<<4 | r;  L1: i = (t>>4)<<8 | r<<4 | (t&15);
//          L2: i = ((r>>2)&3)<<8 | t<<2 | (r&3).
__global__ __launch_bounds__(64) void qsa_main(
    const float* __restrict__ x,
    const float* __restrict__ rx0,
    const float* __restrict__ ry0,
    const float* __restrict__ ry1,
    float* __restrict__ out) {

    __shared__ __align__(16) float reb[PBUF];
    __shared__ __align__(16) float imb[PBUF];

    const int t = threadIdx.x;
    const int n = blockIdx.x;

    // ---- load row (L0 layout): rf[j] = amps (16t+2j, 16t+2j+1) ----
    f32x2 rf[8], mf[8];
    const float* xr = x + ((size_t)n << 10) + (t << 4);
    #pragma unroll
    for (int k = 0; k < 4; ++k) {
        const float4 v = *reinterpret_cast<const float4*>(xr + 4 * k);
        rf[2*k]   = f32x2{v.x, v.y};
        rf[2*k+1] = f32x2{v.z, v.w};
    }

    // ---- per-wire coefficients in lanes 0..9 ----
    float car = 0.f, cai = 0.f, cbr = 0.f, cbi = 0.f, cc1 = 0.f, cs1 = 0.f;
    if (t < NW) {
        float sx, cx, sy0, cy0;
        sincosf(0.5f * rx0[t], &sx,  &cx);
        sincosf(0.5f * ry0[t], &sy0, &cy0);
        sincosf(0.5f * ry1[t], &cs1, &cc1);
        car =  cy0 * cx;  cai =  sy0 * sx;   // fused RY(ry0)*RX(rx0)
        cbr = -sy0 * cx;  cbi = -cy0 * sx;
    }

    // ---- sum of squares -> normalization ----
    f32x2 ssv = {0.f, 0.f};
    #pragma unroll
    for (int j = 0; j < 8; ++j) ssv += rf[j] * rf[j];
    float ss = ssv.x + ssv.y;
    #pragma unroll
    for (int b = 32; b > 0; b >>= 1) ss += __shfl_xor(ss, b, 64);
    const float scale = 1.0f / fmaxf(sqrtf(ss), 1e-12f);

    // ========= layer 1, phase A (L0 bits 0-3 -> wires 9,8,7,6) =========
    {   // wire 9 (within-pair): input is real; fold in normalization
        const float ar = rl(car,9), ai = rl(cai,9), br = rl(cbr,9), bi = rl(cbi,9);
        const f32x2 brN = {br, -br};
        const f32x2 aiP = {ai, -ai};
        #pragma unroll
        for (int j = 0; j < 8; ++j) {
            const f32x2 v = scale * rf[j];
            rf[j] = ar*v  + brN*swap2(v);
            mf[j] = aiP*v + bi*swap2(v);
        }
    }
    cgv<1>(rf, mf, rl(car,8), rl(cai,8), rl(cbr,8), rl(cbi,8));   // wire 8
    cgv<2>(rf, mf, rl(car,7), rl(cai,7), rl(cbr,7), rl(cbi,7));   // wire 7
    cgv<4>(rf, mf, rl(car,6), rl(cai,6), rl(cbr,6), rl(cbi,6));   // wire 6

    // T1: write L0 (b128 per plane), read L1 (b32 per plane)
    #pragma unroll
    for (int k = 0; k < 4; ++k) {
        const int p = PF((t << 4) + 4 * k);
        *reinterpret_cast<float4*>(&reb[p]) =
            make_float4(rf[2*k].x, rf[2*k].y, rf[2*k+1].x, rf[2*k+1].y);
        *reinterpret_cast<float4*>(&imb[p]) =
            make_float4(mf[2*k].x, mf[2*k].y, mf[2*k+1].x, mf[2*k+1].y);
    }
    __syncthreads();
    {
        const int b0 = ((t >> 4) << 8) | (t & 15);
        #pragma unroll
        for (int j = 0; j < 8; ++j) {
            const int p0 = PF(b0 + ((2*j) << 4)), p1 = PF(b0 + ((2*j+1) << 4));
            rf[j] = f32x2{reb[p0], reb[p1]};
            mf[j] = f32x2{imb[p0], imb[p1]};
        }
    }

    // ========= layer 1, phase B (L1 bits 4-7 -> wires 5,4,3,2) =========
    cgv0  (rf, mf, rl(car,5), rl(cai,5), rl(cbr,5), rl(cbi,5));   // wire 5
    cgv<1>(rf, mf, rl(car,4), rl(cai,4), rl(cbr,4), rl(cbi,4));   // wire 4
    cgv<2>(rf, mf, rl(car,3), rl(cai,3), rl(cbr,3), rl(cbi,3));   // wire 3
    cgv<4>(rf, mf, rl(car,2), rl(cai,2), rl(cbr,2), rl(cbi,2));   // wire 2

    // T2: write L1 (b32), read L2 (b128)
    __syncthreads();
    {
        const int b0 = ((t >> 4) << 8) | (t & 15);
        #pragma unroll
        for (int j = 0; j < 8; ++j) {
            const int p0 = PF(b0 + ((2*j) << 4)), p1 = PF(b0 + ((2*j+1) << 4));
            reb[p0] = rf[j].x; reb[p1] = rf[j].y;
            imb[p0] = mf[j].x; imb[p1] = mf[j].y;
        }
    }
    __syncthreads();
    #pragma unroll
    for (int k = 0; k < 4; ++k) {
        const int p = PF((k << 8) | (t << 2));
        const float4 qr = *reinterpret_cast<const float4*>(&reb[p]);
        const float4 qi = *reinterpret_cast<const float4*>(&imb[p]);
        rf[2*k] = f32x2{qr.x, qr.y}; rf[2*k+1] = f32x2{qr.z, qr.w};
        mf[2*k] = f32x2{qi.x, qi.y}; mf[2*k+1] = f32x2{qi.z, qi.w};
    }

    // ========= layer 1, phase C (L2: r bit2 -> wire 1, r bit3 -> wire 0) ====
    cgv<2>(rf, mf, rl(car,1), rl(cai,1), rl(cbr,1), rl(cbi,1));   // wire 1
    cgv<4>(rf, mf, rl(car,0), rl(cai,0), rl(cbr,0), rl(cbi,0));   // wire 0

    // T3: write L2 (b128), read CNOT-ring gather -> L0 (b32)
    __syncthreads();
    #pragma unroll
    for (int k = 0; k < 4; ++k) {
        const int p = PF((k << 8) | (t << 2));
        *reinterpret_cast<float4*>(&reb[p]) =
            make_float4(rf[2*k].x, rf[2*k].y, rf[2*k+1].x, rf[2*k+1].y);
        *reinterpret_cast<float4*>(&imb[p]) =
            make_float4(mf[2*k].x, mf[2*k].y, mf[2*k+1].x, mf[2*k+1].y);
    }
    __syncthreads();
    {
        const int gt = gperm(t << 4);
        #pragma unroll
        for (int j = 0; j < 8; ++j) {
            const int p0 = PF(gt ^ gperm(2*j)), p1 = PF(gt ^ gperm(2*j+1));
            rf[j] = f32x2{reb[p0], reb[p1]};
            mf[j] = f32x2{imb[p0], imb[p1]};
        }
    }

    // ========= layer 2, phase A2 (L0 -> wires 9,8,7,6) =========
    rgv0  (rf, mf, rl(cc1,9), rl(cs1,9));   // wire 9
    rgv<1>(rf, mf, rl(cc1,8), rl(cs1,8));   // wire 8
    rgv<2>(rf, mf, rl(cc1,7), rl(cs1,7));   // wire 7
    rgv<4>(rf, mf, rl(cc1,6), rl(cs1,6));   // wire 6

    // T4: write L0 (b128), read L1 (b32)
    __syncthreads();
    #pragma unroll
    for (int k = 0; k < 4; ++k) {
        const int p = PF((t << 4) + 4 * k);
        *reinterpret_cast<float4*>(&reb[p]) =
            make_float4(rf[2*k].x, rf[2*k].y, rf[2*k+1].x, rf[2*k+1].y);
        *reinterpret_cast<float4*>(&imb[p]) =
            make_float4(mf[2*k].x, mf[2*k].y, mf[2*k+1].x, mf[2*k+1].y);
    }
    __syncthreads();
    {
        const int b0 = ((t >> 4) << 8) | (t & 15);
        #pragma unroll
        for (int j = 0; j < 8; ++j) {
            const int p0 = PF(b0 + ((2*j) << 4)), p1 = PF(b0 + ((2*j+1) << 4));
            rf[j] = f32x2{reb[p0], reb[p1]};
            mf[j] = f32x2{imb[p0], imb[p1]};
        }
    }

    // ========= layer 2, phase B2 (L1 -> wires 5,4,3,2) =========
    rgv0  (rf, mf, rl(cc1,5), rl(cs1,5));   // wire 5
    rgv<1>(rf, mf, rl(cc1,4), rl(cs1,4));   // wire 4
    rgv<2>(rf, mf, rl(cc1,3), rl(cs1,3));   // wire 3
    rgv<4>(rf, mf, rl(cc1,2), rl(cs1,2));   // wire 2

    // T5: write L1 (b32), read L2 (b128)
    __syncthreads();
    {
        const int b0 = ((t >> 4) << 8) | (t & 15);
        #pragma unroll
        for (int j = 0; j < 8; ++j) {
            const int p0 = PF(b0 + ((2*j) << 4)), p1 = PF(b0 + ((2*j+1) << 4));
            reb[p0] = rf[j].x; reb[p1] = rf[j].y;
            imb[p0] = mf[j].x; imb[p1] = mf[j].y;
        }
    }
    __syncthreads();
    #pragma unroll
    for (int k = 0; k < 4; ++k) {
        const int p = PF((k << 8) | (t << 2));
        const float4 qr = *reinterpret_cast<const float4*>(&reb[p]);
        const float4 qi = *reinterpret_cast<const float4*>(&imb[p]);
        rf[2*k] = f32x2{qr.x, qr.y}; rf[2*k+1] = f32x2{qr.z, qr.w};
        mf[2*k] = f32x2{qi.x, qi.y}; mf[2*k+1] = f32x2{qi.z, qi.w};
    }

    // ========= layer 2, phase C2 (L2 -> wires 1,0) =========
    rgv<2>(rf, mf, rl(cc1,1), rl(cs1,1));   // wire 1
    rgv<4>(rf, mf, rl(cc1,0), rl(cs1,0));   // wire 0

    // ---- Z expectations (L2: amp r = 2j + pair-lane) ----
    // wire0 <- r bit3 (j bit2), wire1 <- r bit2 (j bit1),
    // wire8 <- r bit1 (j bit0), wire9 <- r bit0 (pair-internal),
    // wires 2..7 <- t bits 5..0 (WHT over lanes).
    f32x2 accP = {0,0}, acc9 = {0,0}, acc8 = {0,0}, acc1 = {0,0}, acc0 = {0,0};
    const f32x2 pm = {1.f, -1.f};
    #pragma unroll
    for (int j = 0; j < 8; ++j) {
        const f32x2 p = rf[j]*rf[j] + mf[j]*mf[j];
        accP += p;
        acc9 += pm * p;
        if (j & 1) acc8 -= p; else acc8 += p;
        if (j & 2) acc1 -= p; else acc1 += p;
        if (j & 4) acc0 -= p; else acc0 += p;
    }
    float P  = accP.x + accP.y;
    float a9 = acc9.x + acc9.y;
    float a8 = acc8.x + acc8.y;
    float a1 = acc1.x + acc1.y;
    float a0 = acc0.x + acc0.y;
    #pragma unroll
    for (int b = 1; b < 64; b <<= 1) {
        a0 += __shfl_xor(a0, b, 64);
        a1 += __shfl_xor(a1, b, 64);
        a8 += __shfl_xor(a8, b, 64);
        a9 += __shfl_xor(a9, b, 64);
        const float e = __shfl_xor(P, b, 64);
        P = (t & b) ? (e - P) : (e + P);   // WHT over lane bits
    }
    float* o = out + (size_t)n * NW;
    if (t == 0) { o[0] = a0; o[1] = a1; o[8] = a8; o[9] = a9; }
    if (t == 32) o[2] = P;   // wire 2 <- t bit 5
    if (t == 16) o[3] = P;   // wire 3 <- t bit 4
    if (t ==  8) o[4] = P;   // wire 4 <- t bit 3
    if (t ==  4) o[5] = P;   // wire 5 <- t bit 2
    if (t ==  2) o[6] = P;   // wire 6 <- t bit 1
    if (t ==  1) o[7] = P;   // wire 7 <- t bit 0
}

extern "C" void kernel_launch(void* const* d_in, const int* in_sizes, int n_in,
                              void* d_out, int out_size, void* d_ws, size_t ws_size,
                              hipStream_t stream) {
    const float* x   = (const float*)d_in[0];
    const float* rx0 = (const float*)d_in[1];
    const float* ry0 = (const float*)d_in[2];
    const float* ry1 = (const float*)d_in[3];
    float* out = (float*)d_out;
    const int nstates = in_sizes[0] >> 10;   // 4096
    qsa_main<<<nstates, 64, 0, stream>>>(x, rx0, ry0, ry1, out);
}